// Round 4
// baseline (173.124 us; speedup 1.0000x reference)
//
#include <hip/hip_runtime.h>
#include <cmath>

typedef float f32x4 __attribute__((ext_vector_type(4)));
typedef float f32x2 __attribute__((ext_vector_type(2)));

#define TT 8192
#define NV 65
#define KTILE 2048
#define NBLK 640  // 384 full tiles (dispatched first) + 256 diagonal tiles

__device__ __forceinline__ float dot4acc(f32x4 a, f32x4 b, float acc) {
  acc = fmaf(a[0], b[0], acc);
  acc = fmaf(a[1], b[1], acc);
  acc = fmaf(a[2], b[2], acc);
  acc = fmaf(a[3], b[3], acc);
  return acc;
}

// Kernel A: cpt[b*6+e][t] = softmax(embed_w[x])[b,t,e]; also zeroes wsum.
__global__ __launch_bounds__(256) void cp_kernel(const int* __restrict__ x,
                                                 const float* __restrict__ ew,
                                                 float* __restrict__ cpt,
                                                 float* __restrict__ wsum) {
  int n = blockIdx.x * 256 + threadIdx.x;  // n = b*8192 + t
  int b = n >> 13, t = n & 8191;
  int xv = x[n];
  float v[6];
#pragma unroll
  for (int e = 0; e < 6; ++e) v[e] = ew[xv * 6 + e];
  float m = v[0];
#pragma unroll
  for (int e = 1; e < 6; ++e) m = fmaxf(m, v[e]);
  float s = 0.f;
#pragma unroll
  for (int e = 0; e < 6; ++e) { v[e] = expf(v[e] - m); s += v[e]; }
  float inv = 1.f / s;
#pragma unroll
  for (int e = 0; e < 6; ++e) cpt[(b * 6 + e) * TT + t] = v[e] * inv;
  f32x2 z2 = {0.f, 0.f};
#pragma unroll
  for (int i = 0; i < 3; ++i)
    *reinterpret_cast<f32x2*>(&wsum[6 * n + 2 * i]) = z2;
}

// Kernel B: wsum[t][24] += tril(W)[32-row x 2048-k tile] @ cp.
// 4 independent waves (8 rows each), no LDS, no syncthreads, no VGPR cap.
// Lane = (rowsel = lane>>4, k16 = lane&15); lane owns rows {rb+rowsel,
// rb+rowsel+4} x 24 e -> acc[2][24] (48 VGPR). k16 splits k 16-way (x f32x4).
// Reduction: 4-step butterfly over k16 + lane-predicated atomics.
__global__ __launch_bounds__(256) void sticky_B(const float* __restrict__ W,
                                                const float* __restrict__ cpt,
                                                float* __restrict__ wsum) {
  // bid -> (rt, kt); full tiles first (long poles dispatch early)
  int bid = blockIdx.x;
  int rt, kt;
  if (bid < 64) { rt = 64 + bid; kt = 0; }
  else if (bid < 192) { int q = bid - 64; rt = 128 + (q >> 1); kt = q & 1; }
  else if (bid < 384) { int q = bid - 192; int q3 = q / 3; rt = 192 + q3; kt = q - 3 * q3; }
  else { rt = bid - 384; kt = rt >> 6; }  // diagonal (partial) tiles

  const int tid = threadIdx.x;
  const int w = tid >> 6, lane = tid & 63;
  const int rowsel = lane >> 4, k16 = lane & 15;
  const int R = rt * 32;
  const int row0 = R + 8 * w + rowsel;          // second row = row0 + 4
  const int k0 = kt * KTILE;
  const int kend = min(k0 + KTILE, 32 * rt + 32);
  const int nit = (kend - k0 + 63) >> 6;        // 64 k per iter

  const float* wp0 = &W[(size_t)row0 * TT + k0 + k16 * 4];
  const float* wp1 = wp0 + 4 * (size_t)TT;

  float acc[2][24];
#pragma unroll
  for (int r = 0; r < 2; ++r)
#pragma unroll
    for (int e = 0; e < 24; ++e) acc[r][e] = 0.f;

  // W prefetched one iteration ahead; upper-triangle of position_mask is
  // exactly 0 (tril in setup) so in-tile over-read past the diagonal adds 0.
  f32x4 w0 = __builtin_nontemporal_load(reinterpret_cast<const f32x4*>(wp0));
  f32x4 w1 = __builtin_nontemporal_load(reinterpret_cast<const f32x4*>(wp1));
#pragma unroll 1
  for (int it = 0; it < nit; ++it) {
    const int nxt = (it + 1 < nit) ? (it + 1) * 64 : it * 64;
    f32x4 nw0 = __builtin_nontemporal_load(
        reinterpret_cast<const f32x4*>(wp0 + nxt));
    f32x4 nw1 = __builtin_nontemporal_load(
        reinterpret_cast<const f32x4*>(wp1 + nxt));
    const int off = k0 + it * 64 + k16 * 4;  // 32-bit offsets -> sbase+voffset
#pragma unroll
    for (int e = 0; e < 24; ++e) {
      f32x4 c = *reinterpret_cast<const f32x4*>(&cpt[off + e * TT]);
      acc[0][e] = dot4acc(w0, c, acc[0][e]);
      acc[1][e] = dot4acc(w1, c, acc[1][e]);
    }
    w0 = nw0;
    w1 = nw1;
  }

  // reduce over the 16-way k split; one lane per 16-group flushes each value
#pragma unroll
  for (int r = 0; r < 2; ++r)
#pragma unroll
    for (int e = 0; e < 24; ++e) {
      float v = acc[r][e];
      v += __shfl_xor(v, 1);
      v += __shfl_xor(v, 2);
      v += __shfl_xor(v, 4);
      v += __shfl_xor(v, 8);
      if (k16 == ((r * 24 + e) & 15))
        atomicAdd(&wsum[(row0 + 4 * r) * 24 + e], v);
    }
}

// Kernel C: one thread per output element, out[b][t][v].
__global__ __launch_bounds__(256) void epi_kernel(
    const float* __restrict__ cpt, const float* __restrict__ wsum,
    const float* __restrict__ rtp, const float* __restrict__ tp,
    const float* __restrict__ CT, const float* __restrict__ RT,
    const float* __restrict__ OM, float* __restrict__ out) {
  int n = blockIdx.x * 256 + threadIdx.x;  // exactly 4*8192*65 threads
  int bt = n / NV;
  int v = n - bt * NV;
  int b = bt >> 13, t = bt & 8191;
  float cp6[6], ws6[6];
#pragma unroll
  for (int e = 0; e < 6; ++e) {
    cp6[e] = cpt[(b * 6 + e) * TT + t];
    ws6[e] = wsum[t * 24 + b * 6 + e];
  }
  float score = 0.f;
#pragma unroll
  for (int e = 0; e < 6; ++e) score = fmaf(cp6[e], ws6[e], score);
  float rt = rtp[0];
  float temp = tp[0];
  float z = (score - rt * rt) / (temp * temp);
  float reset = 1.f / (1.f + expf(-z));  // saturates correctly at extremes
  float o = 0.f;
#pragma unroll
  for (int c = 0; c < 6; ++c) {
    float tc = 0.f, rc = 0.f;
#pragma unroll
    for (int e = 0; e < 6; ++e) {
      tc = fmaf(cp6[e], CT[e * 6 + c], tc);
      rc = fmaf(cp6[e], RT[e * 6 + c], rc);
    }
    float nc = reset * rc + (1.f - reset) * tc;
    o = fmaf(nc, OM[c * NV + v], o);
  }
  out[n] = o;
}

extern "C" void kernel_launch(void* const* d_in, const int* in_sizes, int n_in,
                              void* d_out, int out_size, void* d_ws, size_t ws_size,
                              hipStream_t stream) {
  const int* x = (const int*)d_in[0];
  const float* ew = (const float*)d_in[1];
  const float* W = (const float*)d_in[2];
  const float* rtp = (const float*)d_in[3];
  const float* tp = (const float*)d_in[4];
  const float* CT = (const float*)d_in[5];
  const float* RT = (const float*)d_in[6];
  const float* OM = (const float*)d_in[7];
  float* out = (float*)d_out;
  float* cpt = (float*)d_ws;             // 24*8192 f32 = 786 KB
  float* wsum = (float*)d_ws + 24 * TT;  // 8192*24 f32 = 786 KB

  hipLaunchKernelGGL(cp_kernel, dim3(128), dim3(256), 0, stream, x, ew, cpt, wsum);
  hipLaunchKernelGGL(sticky_B, dim3(NBLK), dim3(256), 0, stream, W, cpt, wsum);
  int nout = 4 * TT * NV;  // 2,129,920 = 8320 * 256 exactly
  hipLaunchKernelGGL(epi_kernel, dim3(nout / 256), dim3(256), 0, stream,
                     cpt, wsum, rtp, tp, CT, RT, OM, out);
}

// Round 5
// 103.814 us; speedup vs baseline: 1.6676x; 1.6676x over previous
//
#include <hip/hip_runtime.h>
#include <cmath>

typedef float f32x4 __attribute__((ext_vector_type(4)));
typedef float f32x2 __attribute__((ext_vector_type(2)));

#define TT 8192
#define NV 65
#define STG 256   // k per LDS stage
#define NBLK 640

__device__ __forceinline__ float dot4acc(f32x4 a, f32x4 b, float acc) {
  acc = fmaf(a[0], b[0], acc);
  acc = fmaf(a[1], b[1], acc);
  acc = fmaf(a[2], b[2], acc);
  acc = fmaf(a[3], b[3], acc);
  return acc;
}

// Kernel A: cpt[b*6+e][t] = softmax(embed_w[x])[b,t,e]; also zeroes wsum.
__global__ __launch_bounds__(256) void cp_kernel(const int* __restrict__ x,
                                                 const float* __restrict__ ew,
                                                 float* __restrict__ cpt,
                                                 float* __restrict__ wsum) {
  int n = blockIdx.x * 256 + threadIdx.x;  // n = b*8192 + t
  int b = n >> 13, t = n & 8191;
  int xv = x[n];
  float v[6];
#pragma unroll
  for (int e = 0; e < 6; ++e) v[e] = ew[xv * 6 + e];
  float m = v[0];
#pragma unroll
  for (int e = 1; e < 6; ++e) m = fmaxf(m, v[e]);
  float s = 0.f;
#pragma unroll
  for (int e = 0; e < 6; ++e) { v[e] = expf(v[e] - m); s += v[e]; }
  float inv = 1.f / s;
#pragma unroll
  for (int e = 0; e < 6; ++e) cpt[(b * 6 + e) * TT + t] = v[e] * inv;
  f32x2 z2 = {0.f, 0.f};
#pragma unroll
  for (int i = 0; i < 3; ++i)
    *reinterpret_cast<f32x2*>(&wsum[6 * n + 2 * i]) = z2;
}

// Kernel B: wsum[t][24] += tril(W)[32-row x 2048-k tile] @ cp.
// 4 waves x (8 rows each: lane rowsel 2b x k16 4b, 2 rows/lane, acc[2][24]).
// cp staged in LDS per 256-k (cuts chip L2 traffic 1.7GB -> ~0.13GB);
// W batch-loaded one full stage ahead into regs, per-lane bounds-guarded.
// __launch_bounds__(256,1): allow high VGPR so acc NEVER spills (round-4
// lesson: default occupancy targeting spilled acc -> VGPR_Count 44, 160us).
__global__ __launch_bounds__(256, 1) void sticky_B(const float* __restrict__ W,
                                                   const float* __restrict__ cpt,
                                                   float* __restrict__ wsum) {
  __shared__ __align__(16) float cp_lds[24][STG];
  // bid -> (rt, kt): long tiles dispatched first, shortest diagonals last
  int bid = blockIdx.x;
  int rt, kt;
  if (bid < 64) { rt = 64 + bid; kt = 0; }
  else if (bid < 192) { int q = bid - 64; rt = 128 + (q >> 1); kt = q & 1; }
  else if (bid < 384) { int q = bid - 192; int q3 = q / 3; rt = 192 + q3; kt = q - 3 * q3; }
  else if (bid < 448) { rt = 192 + (bid - 384); kt = 3; }       // long diagonals
  else { rt = 639 - bid; kt = rt >> 6; }                        // rt 191..0 short

  const int tid = threadIdx.x;
  const int w = tid >> 6, lane = tid & 63;
  const int rowsel = lane >> 4, k16 = lane & 15;
  const int R = rt * 32;
  const int row0 = R + 8 * w + rowsel;  // second row = row0 + 4
  const int k0 = kt * 2048;
  const int kend = min(k0 + 2048, R + 32);
  const int nst = (kend - k0 + STG - 1) >> 8;

  const float* wp0 = W + (size_t)row0 * TT;
  const float* wp1 = wp0 + 4 * (size_t)TT;

  float acc[2][24];
#pragma unroll
  for (int r = 0; r < 2; ++r)
#pragma unroll
    for (int e = 0; e < 24; ++e) acc[r][e] = 0.f;

  f32x4 wc[2][4], wn[2][4];
  const f32x4 vz = {0.f, 0.f, 0.f, 0.f};
#define LOADW(dst, s)                                                        \
  {                                                                          \
    _Pragma("unroll") for (int jj = 0; jj < 4; ++jj) {                       \
      int kvec = k0 + (s)*STG + jj * 64 + k16 * 4;                           \
      bool vld = kvec < kend; /* tril zeros make padding-with-0 exact */     \
      dst[0][jj] = vld ? __builtin_nontemporal_load(                         \
                             reinterpret_cast<const f32x4*>(wp0 + kvec))     \
                       : vz;                                                 \
      dst[1][jj] = vld ? __builtin_nontemporal_load(                         \
                             reinterpret_cast<const f32x4*>(wp1 + kvec))     \
                       : vz;                                                 \
    }                                                                        \
  }

  LOADW(wc, 0);
#pragma unroll 1
  for (int s = 0; s < nst; ++s) {
    __syncthreads();
    const int ks = k0 + s * STG;
    // stage cp[24][256] (24 KB): 6 f32x4 per thread, coalesced; column
    // clamped to stay inside cpt (clamped dups pair with guaranteed w=0)
#pragma unroll
    for (int i = 0; i < 6; ++i) {
      int f = tid + 256 * i;
      int e = f >> 6, c4 = (f & 63) * 4;
      int col = min(ks + c4, TT - 4);
      *reinterpret_cast<f32x4*>(&cp_lds[e][c4]) =
          *reinterpret_cast<const f32x4*>(&cpt[e * TT + col]);
    }
    if (s + 1 < nst) LOADW(wn, s + 1);
    __syncthreads();
    // 4 x 64-k iterations, all uniform (zero-padded W handles the tail)
#pragma unroll
    for (int it = 0; it < 4; ++it) {
      const int kl = it * 64 + k16 * 4;
#pragma unroll
      for (int e = 0; e < 24; ++e) {
        f32x4 c = *reinterpret_cast<const f32x4*>(&cp_lds[e][kl]);
        acc[0][e] = dot4acc(wc[0][it], c, acc[0][e]);
        acc[1][e] = dot4acc(wc[1][it], c, acc[1][e]);
      }
    }
#pragma unroll
    for (int r = 0; r < 2; ++r)
#pragma unroll
      for (int jj = 0; jj < 4; ++jj) wc[r][jj] = wn[r][jj];
  }

  // reduce the 16-way k split; one lane per 16-group flushes each value
#pragma unroll
  for (int r = 0; r < 2; ++r)
#pragma unroll
    for (int e = 0; e < 24; ++e) {
      float v = acc[r][e];
      v += __shfl_xor(v, 1);
      v += __shfl_xor(v, 2);
      v += __shfl_xor(v, 4);
      v += __shfl_xor(v, 8);
      if (k16 == ((r * 24 + e) & 15))
        atomicAdd(&wsum[(row0 + 4 * r) * 24 + e], v);
    }
}

// Kernel C: one thread per output element, out[b][t][v].
__global__ __launch_bounds__(256) void epi_kernel(
    const float* __restrict__ cpt, const float* __restrict__ wsum,
    const float* __restrict__ rtp, const float* __restrict__ tp,
    const float* __restrict__ CT, const float* __restrict__ RT,
    const float* __restrict__ OM, float* __restrict__ out) {
  int n = blockIdx.x * 256 + threadIdx.x;  // exactly 4*8192*65 threads
  int bt = n / NV;
  int v = n - bt * NV;
  int b = bt >> 13, t = bt & 8191;
  float cp6[6], ws6[6];
#pragma unroll
  for (int e = 0; e < 6; ++e) {
    cp6[e] = cpt[(b * 6 + e) * TT + t];
    ws6[e] = wsum[t * 24 + b * 6 + e];
  }
  float score = 0.f;
#pragma unroll
  for (int e = 0; e < 6; ++e) score = fmaf(cp6[e], ws6[e], score);
  float rt = rtp[0];
  float temp = tp[0];
  float z = (score - rt * rt) / (temp * temp);
  float reset = 1.f / (1.f + expf(-z));  // saturates correctly at extremes
  float o = 0.f;
#pragma unroll
  for (int c = 0; c < 6; ++c) {
    float tc = 0.f, rc = 0.f;
#pragma unroll
    for (int e = 0; e < 6; ++e) {
      tc = fmaf(cp6[e], CT[e * 6 + c], tc);
      rc = fmaf(cp6[e], RT[e * 6 + c], rc);
    }
    float nc = reset * rc + (1.f - reset) * tc;
    o = fmaf(nc, OM[c * NV + v], o);
  }
  out[n] = o;
}

extern "C" void kernel_launch(void* const* d_in, const int* in_sizes, int n_in,
                              void* d_out, int out_size, void* d_ws, size_t ws_size,
                              hipStream_t stream) {
  const int* x = (const int*)d_in[0];
  const float* ew = (const float*)d_in[1];
  const float* W = (const float*)d_in[2];
  const float* rtp = (const float*)d_in[3];
  const float* tp = (const float*)d_in[4];
  const float* CT = (const float*)d_in[5];
  const float* RT = (const float*)d_in[6];
  const float* OM = (const float*)d_in[7];
  float* out = (float*)d_out;
  float* cpt = (float*)d_ws;             // 24*8192 f32 = 786 KB
  float* wsum = (float*)d_ws + 24 * TT;  // 8192*24 f32 = 786 KB

  hipLaunchKernelGGL(cp_kernel, dim3(128), dim3(256), 0, stream, x, ew, cpt, wsum);
  hipLaunchKernelGGL(sticky_B, dim3(NBLK), dim3(256), 0, stream, W, cpt, wsum);
  int nout = 4 * TT * NV;  // 2,129,920 = 8320 * 256 exactly
  hipLaunchKernelGGL(epi_kernel, dim3(nout / 256), dim3(256), 0, stream,
                     cpt, wsum, rtp, tp, CT, RT, OM, out);
}